// Round 2
// baseline (534.567 us; speedup 1.0000x reference)
//
#include <hip/hip_runtime.h>
#include <hip/hip_bf16.h>

// Problem constants (from reference)
#define NN 50000
#define NE 800000
#define HD 128

typedef unsigned short u16;

__device__ __forceinline__ float bf2f(u16 v) {
    union { unsigned int u; float f; } x; x.u = ((unsigned int)v) << 16; return x.f;
}
__device__ __forceinline__ u16 f2bf(float f) {
    union { unsigned int u; float f; } x; x.f = f;
    unsigned int r = x.u + 0x7fff + ((x.u >> 16) & 1);
    return (u16)(r >> 16);
}
__device__ __forceinline__ float eluf(float v) { return v > 0.f ? v : expm1f(v); }

// K1: Wcomb[k][c] : c<128 -> Wown = we0[k] + we0[256+k] ; c>=128 -> Wnei = we0[128+k] - we0[256+k]
__global__ void k_combine(const float* __restrict__ we0, float* __restrict__ wcomb) {
    int i = blockIdx.x * 256 + threadIdx.x;   // 128*256 total
    int k = i >> 8, c = i & 255;
    float v;
    if (c < 128) v = we0[k * 128 + c] + we0[(256 + k) * 128 + c];
    else { int cc = c - 128; v = we0[(128 + k) * 128 + cc] - we0[(256 + k) * 128 + cc]; }
    wcomb[k * 256 + c] = v;
}

// K2: R = x @ Wcomb ; P2[n][0:128]=P (bf16), P2[n][128:256]=x (bf16), Q[n][0:128] (bf16)
__global__ __launch_bounds__(256) void k_pq(const float* __restrict__ x,
                                            const float* __restrict__ wcomb,
                                            u16* __restrict__ p2, u16* __restrict__ q) {
    __shared__ float xs[32 * 128];
    int r0 = blockIdx.x * 32, tid = threadIdx.x;
    for (int i = tid; i < 32 * 128; i += 256) {
        int r = i >> 7, c = i & 127; int n = r0 + r;
        xs[i] = (n < NN) ? x[(size_t)n * 128 + c] : 0.f;
    }
    __syncthreads();
    int c = tid;  // 0..255
    float acc[32];
#pragma unroll
    for (int j = 0; j < 32; j++) acc[j] = 0.f;
    for (int k0 = 0; k0 < 128; k0 += 8) {
        float w[8];
#pragma unroll
        for (int t = 0; t < 8; t++) w[t] = wcomb[(k0 + t) * 256 + c];
#pragma unroll
        for (int j = 0; j < 32; j++) {
            const float4* ap = (const float4*)&xs[j * 128 + k0];
            float4 a0 = ap[0], a1 = ap[1];
            acc[j] += a0.x * w[0] + a0.y * w[1] + a0.z * w[2] + a0.w * w[3]
                    + a1.x * w[4] + a1.y * w[5] + a1.z * w[6] + a1.w * w[7];
        }
    }
    for (int j = 0; j < 32; j++) {
        int n = r0 + j; if (n >= NN) break;
        if (c < 128) {
            p2[(size_t)n * 256 + c] = f2bf(acc[j]);
        } else {
            int cc = c - 128;
            q[(size_t)n * 128 + cc] = f2bf(acc[j]);
            p2[(size_t)n * 256 + 128 + cc] = f2bf(xs[j * 128 + cc]);
        }
    }
}

// K3: in-degree histogram (edge_index arrives as int32 per harness conversion)
__global__ void k_hist(const int* __restrict__ ei, int* __restrict__ cnt) {
    int e = blockIdx.x * 256 + threadIdx.x;
    if (e < NE) { int d = ei[NE + e]; atomicAdd(&cnt[d], 1); }
}

// K4a: per-block (512) inclusive scan
__global__ void k_scan1(const int* __restrict__ cnt, int* __restrict__ incl, int* __restrict__ bsum) {
    __shared__ int s[512];
    int i = blockIdx.x * 512 + threadIdx.x;
    int v = (i < NN) ? cnt[i] : 0;
    s[threadIdx.x] = v; __syncthreads();
    for (int off = 1; off < 512; off <<= 1) {
        int t = (threadIdx.x >= (unsigned)off) ? s[threadIdx.x - off] : 0;
        __syncthreads();
        s[threadIdx.x] += t; __syncthreads();
    }
    if (i < NN) incl[i] = s[threadIdx.x];
    if (threadIdx.x == 511) bsum[blockIdx.x] = s[511];
}

// K4b: exclusive scan of block sums (nb <= 128)
__global__ void k_scan2(int* __restrict__ bsum, int nb) {
    __shared__ int s[128];
    int t = threadIdx.x;
    s[t] = (t < nb) ? bsum[t] : 0;
    __syncthreads();
    if (t == 0) { int run = 0; for (int b = 0; b < nb; b++) { int v = s[b]; s[b] = run; run += v; } }
    __syncthreads();
    if (t < nb) bsum[t] = s[t];
}

// K4c: offs[i+1] = incl[i]+bpre ; cursor[i] = exclusive offset
__global__ void k_scan3(const int* __restrict__ incl, const int* __restrict__ bsum,
                        const int* __restrict__ cnt, int* __restrict__ offs, int* __restrict__ cursor) {
    int i = blockIdx.x * 512 + threadIdx.x;
    if (i < NN) {
        int e = incl[i] + bsum[i >> 9];
        offs[i + 1] = e;
        cursor[i] = e - cnt[i];
        if (i == 0) offs[0] = 0;
    }
}

// K5: scatter edge srcs into CSR slots grouped by dst
__global__ void k_slots(const int* __restrict__ ei, int* __restrict__ cursor, int* __restrict__ srcs) {
    int e = blockIdx.x * 256 + threadIdx.x;
    if (e < NE) {
        int d = ei[NE + e];
        int p = atomicAdd(&cursor[d], 1);
        srcs[p] = ei[e];
    }
}

__device__ __forceinline__ void accum4(float& a0, float& a1, float& a2, float& a3,
                                       ushort4 v, float q0, float q1, float q2, float q3, bool lo) {
    float t0 = bf2f(v.x) + q0, t1 = bf2f(v.y) + q1, t2 = bf2f(v.z) + q2, t3 = bf2f(v.w) + q3;
    a0 += lo ? eluf(t0) : t0;
    a1 += lo ? eluf(t1) : t1;
    a2 += lo ? eluf(t2) : t2;
    a3 += lo ? eluf(t3) : t3;
}

// K6: one wave per node: esum[n] = sum_e ELU(P[src]+Q[n]) (lanes 0-31),
//     xsum[n] = sum_e x[src] (lanes 32-63). Writes esumx[n][0:256] in bf16.
__global__ __launch_bounds__(256) void k_agg(const u16* __restrict__ p2, const u16* __restrict__ qb,
                                             const int* __restrict__ offs, const int* __restrict__ srcs,
                                             u16* __restrict__ esumx) {
    int wave = threadIdx.x >> 6, lane = threadIdx.x & 63;
    int n = blockIdx.x * 4 + wave;
    if (n >= NN) return;
    int beg = offs[n], end = offs[n + 1];
    bool lo = lane < 32;
    float q0 = 0.f, q1 = 0.f, q2 = 0.f, q3 = 0.f;
    if (lo) {
        ushort4 qv = *(const ushort4*)(qb + (size_t)n * 128 + lane * 4);
        q0 = bf2f(qv.x); q1 = bf2f(qv.y); q2 = bf2f(qv.z); q3 = bf2f(qv.w);
    }
    float a0 = 0.f, a1 = 0.f, a2 = 0.f, a3 = 0.f;
    int s = beg;
    for (; s + 4 <= end; s += 4) {
        int sr0 = srcs[s], sr1 = srcs[s + 1], sr2 = srcs[s + 2], sr3 = srcs[s + 3];
        ushort4 v0 = *(const ushort4*)(p2 + (size_t)sr0 * 256 + lane * 4);
        ushort4 v1 = *(const ushort4*)(p2 + (size_t)sr1 * 256 + lane * 4);
        ushort4 v2 = *(const ushort4*)(p2 + (size_t)sr2 * 256 + lane * 4);
        ushort4 v3 = *(const ushort4*)(p2 + (size_t)sr3 * 256 + lane * 4);
        accum4(a0, a1, a2, a3, v0, q0, q1, q2, q3, lo);
        accum4(a0, a1, a2, a3, v1, q0, q1, q2, q3, lo);
        accum4(a0, a1, a2, a3, v2, q0, q1, q2, q3, lo);
        accum4(a0, a1, a2, a3, v3, q0, q1, q2, q3, lo);
    }
    for (; s < end; ++s) {
        int sr = srcs[s];
        ushort4 v = *(const ushort4*)(p2 + (size_t)sr * 256 + lane * 4);
        accum4(a0, a1, a2, a3, v, q0, q1, q2, q3, lo);
    }
    ushort4 o = { f2bf(a0), f2bf(a1), f2bf(a2), f2bf(a3) };
    *(ushort4*)(esumx + (size_t)n * 256 + lane * 4) = o;
}

// K7: per 32-row tile: m = (esum@We1 + xsum - cnt*x)/max(cnt,1);
//     out = x + ELU(x@Wn0a + m@Wn0b)@Wn1
__global__ __launch_bounds__(256) void k_node(const float* __restrict__ x, const u16* __restrict__ esumx,
                                              const int* __restrict__ offs, const float* __restrict__ we1,
                                              const float* __restrict__ wn0, const float* __restrict__ wn1,
                                              float* __restrict__ out) {
    __shared__ float A[32 * 128];  // esum, later hidden
    __shared__ float B[32 * 128];  // x
    __shared__ float C[32 * 128];  // m
    int r0 = blockIdx.x * 32, tid = threadIdx.x;
    for (int i = tid; i < 32 * 128; i += 256) {
        int r = i >> 7, c = i & 127; int n = r0 + r;
        A[i] = (n < NN) ? bf2f(esumx[(size_t)n * 256 + c]) : 0.f;
        B[i] = (n < NN) ? x[(size_t)n * 128 + c] : 0.f;
    }
    __syncthreads();
    int c = tid & 127, rh = tid >> 7;  // rows rh*16 .. rh*16+15
    float acc[16];
#pragma unroll
    for (int j = 0; j < 16; j++) acc[j] = 0.f;
    // stage 1: esum @ We1
    for (int k0 = 0; k0 < 128; k0 += 8) {
        float w[8];
#pragma unroll
        for (int t = 0; t < 8; t++) w[t] = we1[(k0 + t) * 128 + c];
#pragma unroll
        for (int j = 0; j < 16; j++) {
            const float4* ap = (const float4*)&A[(rh * 16 + j) * 128 + k0];
            float4 a0 = ap[0], a1 = ap[1];
            acc[j] += a0.x * w[0] + a0.y * w[1] + a0.z * w[2] + a0.w * w[3]
                    + a1.x * w[4] + a1.y * w[5] + a1.z * w[6] + a1.w * w[7];
        }
    }
    // m
#pragma unroll
    for (int j = 0; j < 16; j++) {
        int r = rh * 16 + j, n = r0 + r;
        float m = 0.f;
        if (n < NN) {
            float cntf = (float)(offs[n + 1] - offs[n]);
            float xs = bf2f(esumx[(size_t)n * 256 + 128 + c]);
            float xv = B[r * 128 + c];
            m = (acc[j] + xs - cntf * xv) / fmaxf(cntf, 1.f);
        }
        C[r * 128 + c] = m;
    }
    __syncthreads();
    // stage 2: hidden = ELU(x@Wn0[0:128] + m@Wn0[128:256])
    float acc2[16];
#pragma unroll
    for (int j = 0; j < 16; j++) acc2[j] = 0.f;
    for (int k0 = 0; k0 < 128; k0 += 8) {
        float w[8];
#pragma unroll
        for (int t = 0; t < 8; t++) w[t] = wn0[(k0 + t) * 128 + c];
#pragma unroll
        for (int j = 0; j < 16; j++) {
            const float4* ap = (const float4*)&B[(rh * 16 + j) * 128 + k0];
            float4 a0 = ap[0], a1 = ap[1];
            acc2[j] += a0.x * w[0] + a0.y * w[1] + a0.z * w[2] + a0.w * w[3]
                     + a1.x * w[4] + a1.y * w[5] + a1.z * w[6] + a1.w * w[7];
        }
    }
    for (int k0 = 0; k0 < 128; k0 += 8) {
        float w[8];
#pragma unroll
        for (int t = 0; t < 8; t++) w[t] = wn0[(128 + k0 + t) * 128 + c];
#pragma unroll
        for (int j = 0; j < 16; j++) {
            const float4* ap = (const float4*)&C[(rh * 16 + j) * 128 + k0];
            float4 a0 = ap[0], a1 = ap[1];
            acc2[j] += a0.x * w[0] + a0.y * w[1] + a0.z * w[2] + a0.w * w[3]
                     + a1.x * w[4] + a1.y * w[5] + a1.z * w[6] + a1.w * w[7];
        }
    }
    __syncthreads();  // stage-1 reads of A done everywhere -> safe to overwrite
#pragma unroll
    for (int j = 0; j < 16; j++) {
        float h = acc2[j];
        A[(rh * 16 + j) * 128 + c] = (h > 0.f) ? h : expm1f(h);
    }
    __syncthreads();
    // stage 3: out = x + hidden@Wn1
    float acc3[16];
#pragma unroll
    for (int j = 0; j < 16; j++) acc3[j] = 0.f;
    for (int k0 = 0; k0 < 128; k0 += 8) {
        float w[8];
#pragma unroll
        for (int t = 0; t < 8; t++) w[t] = wn1[(k0 + t) * 128 + c];
#pragma unroll
        for (int j = 0; j < 16; j++) {
            const float4* ap = (const float4*)&A[(rh * 16 + j) * 128 + k0];
            float4 a0 = ap[0], a1 = ap[1];
            acc3[j] += a0.x * w[0] + a0.y * w[1] + a0.z * w[2] + a0.w * w[3]
                     + a1.x * w[4] + a1.y * w[5] + a1.z * w[6] + a1.w * w[7];
        }
    }
#pragma unroll
    for (int j = 0; j < 16; j++) {
        int r = rh * 16 + j, n = r0 + r;
        if (n < NN) out[(size_t)n * 128 + c] = B[r * 128 + c] + acc3[j];
    }
}

extern "C" void kernel_launch(void* const* d_in, const int* in_sizes, int n_in,
                              void* d_out, int out_size, void* d_ws, size_t ws_size,
                              hipStream_t stream) {
    const float* x       = (const float*)d_in[0];
    const int* ei        = (const int*)d_in[1];   // int64 in reference -> int32 from harness
    const float* we0     = (const float*)d_in[2];
    const float* we1     = (const float*)d_in[3];
    const float* wn0     = (const float*)d_in[4];
    const float* wn1     = (const float*)d_in[5];
    float* out           = (float*)d_out;

    char* w = (char*)d_ws;
    size_t off = 0;
    auto alloc = [&](size_t bytes) -> void* {
        off = (off + 255) & ~(size_t)255;
        void* p = w + off;
        off += bytes;
        return p;
    };
    float* wcomb = (float*)alloc(128 * 256 * sizeof(float));
    u16*   p2    = (u16*)alloc((size_t)NN * 256 * sizeof(u16));
    u16*   qb    = (u16*)alloc((size_t)NN * 128 * sizeof(u16));
    u16*   esumx = (u16*)alloc((size_t)NN * 256 * sizeof(u16));
    int*   cnt   = (int*)alloc((size_t)NN * sizeof(int));
    int*   incl  = (int*)alloc((size_t)NN * sizeof(int));
    int*   offs  = (int*)alloc((size_t)(NN + 1) * sizeof(int));
    int*   cursor= (int*)alloc((size_t)NN * sizeof(int));
    int*   bsum  = (int*)alloc(128 * sizeof(int));
    int*   srcs  = (int*)alloc((size_t)NE * sizeof(int));
    (void)ws_size; (void)in_sizes; (void)n_in; (void)out_size;  // ~68 MB of d_ws used

    hipMemsetAsync(cnt, 0, (size_t)NN * sizeof(int), stream);

    k_combine<<<128, 256, 0, stream>>>(we0, wcomb);
    k_pq<<<(NN + 31) / 32, 256, 0, stream>>>(x, wcomb, p2, qb);
    k_hist<<<(NE + 255) / 256, 256, 0, stream>>>(ei, cnt);
    int nb = (NN + 511) / 512;
    k_scan1<<<nb, 512, 0, stream>>>(cnt, incl, bsum);
    k_scan2<<<1, 128, 0, stream>>>(bsum, nb);
    k_scan3<<<nb, 512, 0, stream>>>(incl, bsum, cnt, offs, cursor);
    k_slots<<<(NE + 255) / 256, 256, 0, stream>>>(ei, cursor, srcs);
    k_agg<<<(NN + 3) / 4, 256, 0, stream>>>(p2, qb, offs, srcs, esumx);
    k_node<<<(NN + 31) / 32, 256, 0, stream>>>(x, esumx, offs, we1, wn0, wn1, out);
}

// Round 3
// 314.244 us; speedup vs baseline: 1.7011x; 1.7011x over previous
//
#include <hip/hip_runtime.h>
#include <hip/hip_bf16.h>

// Problem constants (from reference)
#define NN 50000
#define NE 800000
#define HD 128

typedef unsigned short u16;
typedef __attribute__((ext_vector_type(8))) short short8;
typedef __attribute__((ext_vector_type(4))) float floatx4;
#define MFMA __builtin_amdgcn_mfma_f32_16x16x32_bf16

__device__ __forceinline__ float bf2f(u16 v) {
    union { unsigned int u; float f; } x; x.u = ((unsigned int)v) << 16; return x.f;
}
__device__ __forceinline__ u16 f2bf(float f) {
    union { unsigned int u; float f; } x; x.f = f;
    unsigned int r = x.u + 0x7fff + ((x.u >> 16) & 1);
    return (u16)(r >> 16);
}
__device__ __forceinline__ float eluf(float v) { return v > 0.f ? v : expm1f(v); }

// convert 8 consecutive f32 to a bf16 A-fragment
__device__ __forceinline__ short8 cvt8(const float* p) {
    const float4* q = (const float4*)p;
    float4 a = q[0], b = q[1];
    short8 r;
    r[0] = (short)f2bf(a.x); r[1] = (short)f2bf(a.y); r[2] = (short)f2bf(a.z); r[3] = (short)f2bf(a.w);
    r[4] = (short)f2bf(b.x); r[5] = (short)f2bf(b.y); r[6] = (short)f2bf(b.z); r[7] = (short)f2bf(b.w);
    return r;
}

// K0: weight prep -> bf16 transposed layouts [c][k]
//  wcombt[256][128]: c<128: we0[k][c]+we0[256+k][c] ; c>=128: we0[128+k][cc]-we0[256+k][cc]
//  we1t[128][128], wn0t[128][256], wn1t[128][128]
__global__ void k_wb(const float* __restrict__ we0, const float* __restrict__ we1,
                     const float* __restrict__ wn0, const float* __restrict__ wn1,
                     u16* __restrict__ wcombt, u16* __restrict__ we1t,
                     u16* __restrict__ wn0t, u16* __restrict__ wn1t) {
    int i = blockIdx.x * 256 + threadIdx.x;
    if (i < 32768) {                       // wcombt
        int c = i >> 7, k = i & 127;
        float v;
        if (c < 128) v = we0[k * 128 + c] + we0[(256 + k) * 128 + c];
        else { int cc = c - 128; v = we0[(128 + k) * 128 + cc] - we0[(256 + k) * 128 + cc]; }
        wcombt[i] = f2bf(v);
    } else if (i < 49152) {                // we1t
        int j = i - 32768; int c = j >> 7, k = j & 127;
        we1t[j] = f2bf(we1[k * 128 + c]);
    } else if (i < 81920) {                // wn0t (k = 0..255)
        int j = i - 49152; int c = j >> 8, k = j & 255;
        wn0t[j] = f2bf(wn0[k * 128 + c]);
    } else if (i < 98304) {                // wn1t
        int j = i - 81920; int c = j >> 7, k = j & 127;
        wn1t[j] = f2bf(wn1[k * 128 + c]);
    }
}

// K2: MFMA [P|Q] = x @ Wcomb ; also p2 hi half = x (bf16)
// block: 512 thr = 8 waves x 16 rows; 128 rows/block; 16 col-tiles (256 cols)
__global__ __launch_bounds__(512) void k_pq_mfma(const float* __restrict__ x,
                                                 const u16* __restrict__ wcombt,
                                                 u16* __restrict__ p2, u16* __restrict__ qb) {
    int r0 = blockIdx.x * 128;
    int tid = threadIdx.x, wid = tid >> 6, lane = tid & 63;
    int arow = lane & 15, kblk = lane >> 4;
    // copy x -> p2 hi half (bf16)
    for (int s = tid; s < 128 * 32; s += 512) {
        int r = s >> 5, cb = (s & 31) * 4;
        int n = r0 + r;
        if (n < NN) {
            float4 v = *(const float4*)&x[(size_t)n * 128 + cb];
            ushort4 o = { f2bf(v.x), f2bf(v.y), f2bf(v.z), f2bf(v.w) };
            *(ushort4*)&p2[(size_t)n * 256 + 128 + cb] = o;
        }
    }
    floatx4 acc[16];
#pragma unroll
    for (int n0 = 0; n0 < 16; n0++) acc[n0] = (floatx4)(0.f);
    int nrow = r0 + wid * 16 + arow; if (nrow >= NN) nrow = NN - 1;
#pragma unroll
    for (int ks = 0; ks < 4; ks++) {
        short8 a = cvt8(&x[(size_t)nrow * 128 + ks * 32 + kblk * 8]);
#pragma unroll
        for (int n0 = 0; n0 < 16; n0++) {
            short8 b = *(const short8*)&wcombt[(size_t)(n0 * 16 + arow) * 128 + ks * 32 + kblk * 8];
            acc[n0] = MFMA(a, b, acc[n0], 0, 0, 0);
        }
    }
#pragma unroll
    for (int n0 = 0; n0 < 16; n0++) {
#pragma unroll
        for (int j = 0; j < 4; j++) {
            int n = r0 + wid * 16 + kblk * 4 + j;
            if (n >= NN) continue;
            int col = n0 * 16 + arow;
            u16 v = f2bf(acc[n0][j]);
            if (col < 128) p2[(size_t)n * 256 + col] = v;
            else qb[(size_t)n * 128 + (col - 128)] = v;
        }
    }
}

// K3: in-degree histogram
__global__ void k_hist(const int* __restrict__ ei, int* __restrict__ cnt) {
    int e = blockIdx.x * 256 + threadIdx.x;
    if (e < NE) { int d = ei[NE + e]; atomicAdd(&cnt[d], 1); }
}

// K4a: per-block (512) inclusive scan
__global__ void k_scan1(const int* __restrict__ cnt, int* __restrict__ incl, int* __restrict__ bsum) {
    __shared__ int s[512];
    int i = blockIdx.x * 512 + threadIdx.x;
    int v = (i < NN) ? cnt[i] : 0;
    s[threadIdx.x] = v; __syncthreads();
    for (int off = 1; off < 512; off <<= 1) {
        int t = (threadIdx.x >= (unsigned)off) ? s[threadIdx.x - off] : 0;
        __syncthreads();
        s[threadIdx.x] += t; __syncthreads();
    }
    if (i < NN) incl[i] = s[threadIdx.x];
    if (threadIdx.x == 511) bsum[blockIdx.x] = s[511];
}

// K4b: exclusive scan of block sums (nb <= 128)
__global__ void k_scan2(int* __restrict__ bsum, int nb) {
    __shared__ int s[128];
    int t = threadIdx.x;
    s[t] = (t < nb) ? bsum[t] : 0;
    __syncthreads();
    if (t == 0) { int run = 0; for (int b = 0; b < nb; b++) { int v = s[b]; s[b] = run; run += v; } }
    __syncthreads();
    if (t < nb) bsum[t] = s[t];
}

// K4c
__global__ void k_scan3(const int* __restrict__ incl, const int* __restrict__ bsum,
                        const int* __restrict__ cnt, int* __restrict__ offs, int* __restrict__ cursor) {
    int i = blockIdx.x * 512 + threadIdx.x;
    if (i < NN) {
        int e = incl[i] + bsum[i >> 9];
        offs[i + 1] = e;
        cursor[i] = e - cnt[i];
        if (i == 0) offs[0] = 0;
    }
}

// K5: scatter edge srcs into CSR slots grouped by dst
__global__ void k_slots(const int* __restrict__ ei, int* __restrict__ cursor, int* __restrict__ srcs) {
    int e = blockIdx.x * 256 + threadIdx.x;
    if (e < NE) {
        int d = ei[NE + e];
        int p = atomicAdd(&cursor[d], 1);
        srcs[p] = ei[e];
    }
}

__device__ __forceinline__ void accum4(float& a0, float& a1, float& a2, float& a3,
                                       ushort4 v, float q0, float q1, float q2, float q3, bool lo) {
    float t0 = bf2f(v.x) + q0, t1 = bf2f(v.y) + q1, t2 = bf2f(v.z) + q2, t3 = bf2f(v.w) + q3;
    a0 += lo ? eluf(t0) : t0;
    a1 += lo ? eluf(t1) : t1;
    a2 += lo ? eluf(t2) : t2;
    a3 += lo ? eluf(t3) : t3;
}

// K6: one wave per node. lanes 0-31: esum; lanes 32-63: xsum.
// Epilogue: lo half -> esum/max(cnt,1) ; hi half -> (xsum - cnt*x[n]) / max(cnt,1). bf16 out.
__global__ __launch_bounds__(256) void k_agg(const u16* __restrict__ p2, const u16* __restrict__ qb,
                                             const int* __restrict__ offs, const int* __restrict__ srcs,
                                             u16* __restrict__ esumx) {
    int wave = threadIdx.x >> 6, lane = threadIdx.x & 63;
    int n = blockIdx.x * 4 + wave;
    if (n >= NN) return;
    int beg = offs[n], end = offs[n + 1];
    bool lo = lane < 32;
    float q0 = 0.f, q1 = 0.f, q2 = 0.f, q3 = 0.f;
    if (lo) {
        ushort4 qv = *(const ushort4*)(qb + (size_t)n * 128 + lane * 4);
        q0 = bf2f(qv.x); q1 = bf2f(qv.y); q2 = bf2f(qv.z); q3 = bf2f(qv.w);
    }
    float a0 = 0.f, a1 = 0.f, a2 = 0.f, a3 = 0.f;
    int s = beg;
    for (; s + 8 <= end; s += 8) {
        int sr[8];
#pragma unroll
        for (int j = 0; j < 8; j++) sr[j] = srcs[s + j];
        ushort4 v[8];
#pragma unroll
        for (int j = 0; j < 8; j++) v[j] = *(const ushort4*)(p2 + (size_t)sr[j] * 256 + lane * 4);
#pragma unroll
        for (int j = 0; j < 8; j++) accum4(a0, a1, a2, a3, v[j], q0, q1, q2, q3, lo);
    }
    for (; s < end; ++s) {
        int sr = srcs[s];
        ushort4 v = *(const ushort4*)(p2 + (size_t)sr * 256 + lane * 4);
        accum4(a0, a1, a2, a3, v, q0, q1, q2, q3, lo);
    }
    float cntf = (float)(end - beg);
    float inv = 1.f / fmaxf(cntf, 1.f);
    if (!lo) {
        ushort4 xv = *(const ushort4*)(p2 + (size_t)n * 256 + lane * 4);  // x half
        a0 -= cntf * bf2f(xv.x); a1 -= cntf * bf2f(xv.y);
        a2 -= cntf * bf2f(xv.z); a3 -= cntf * bf2f(xv.w);
    }
    a0 *= inv; a1 *= inv; a2 *= inv; a3 *= inv;
    ushort4 o = { f2bf(a0), f2bf(a1), f2bf(a2), f2bf(a3) };
    *(ushort4*)(esumx + (size_t)n * 256 + lane * 4) = o;
}

// K7: MFMA node MLP. block: 256 thr = 4 waves x 32 rows (2 row-tiles); 128 rows/block.
// tile[128][136] bf16 used as: xsum' -> m -> hidden (in-place per slot, barrier-separated).
// stage1: T = esumx[:,0:128] @ we1t ; m = T + xsum'
// stage2: h = ELU(x@wn0t[:,0:128] + m@wn0t[:,128:256])
// stage3: out = x + h@wn1t
__global__ __launch_bounds__(256) void k_node_mfma(const float* __restrict__ x,
                                                   const u16* __restrict__ esumx,
                                                   const u16* __restrict__ we1t,
                                                   const u16* __restrict__ wn0t,
                                                   const u16* __restrict__ wn1t,
                                                   float* __restrict__ out) {
    __shared__ u16 tile[128 * 136];   // pad 8 bf16 -> 2-way max bank aliasing (free)
    int r0 = blockIdx.x * 128;
    int tid = threadIdx.x, wid = tid >> 6, lane = tid & 63;
    int arow = lane & 15, kblk = lane >> 4;
    // stage xsum' (esumx hi half) into tile
    for (int s = tid; s < 128 * 16; s += 256) {
        int r = s >> 4, cb = (s & 15) * 8;
        int n = r0 + r; if (n >= NN) n = NN - 1;
        *(short8*)&tile[r * 136 + cb] = *(const short8*)&esumx[(size_t)n * 256 + 128 + cb];
    }
    __syncthreads();
    int rbase = wid * 32;
    floatx4 acc[2][8];
#pragma unroll
    for (int rt = 0; rt < 2; rt++)
#pragma unroll
        for (int n0 = 0; n0 < 8; n0++) acc[rt][n0] = (floatx4)(0.f);
    // ---- stage 1: T = esum/cnt @ We1
#pragma unroll
    for (int ks = 0; ks < 4; ks++) {
        short8 a[2];
#pragma unroll
        for (int rt = 0; rt < 2; rt++) {
            int n = r0 + rbase + rt * 16 + arow; if (n >= NN) n = NN - 1;
            a[rt] = *(const short8*)&esumx[(size_t)n * 256 + ks * 32 + kblk * 8];
        }
#pragma unroll
        for (int n0 = 0; n0 < 8; n0++) {
            short8 b = *(const short8*)&we1t[(size_t)(n0 * 16 + arow) * 128 + ks * 32 + kblk * 8];
            acc[0][n0] = MFMA(a[0], b, acc[0][n0], 0, 0, 0);
            acc[1][n0] = MFMA(a[1], b, acc[1][n0], 0, 0, 0);
        }
    }
    // ---- m = T + xsum' (in place in tile)
#pragma unroll
    for (int rt = 0; rt < 2; rt++)
#pragma unroll
        for (int n0 = 0; n0 < 8; n0++)
#pragma unroll
            for (int j = 0; j < 4; j++) {
                int rloc = rbase + rt * 16 + kblk * 4 + j;
                int col = n0 * 16 + arow;
                float m = acc[rt][n0][j] + bf2f(tile[rloc * 136 + col]);
                tile[rloc * 136 + col] = f2bf(m);
            }
    __syncthreads();
    // ---- stage 2: h = ELU(x@Wn0a + m@Wn0b)
#pragma unroll
    for (int rt = 0; rt < 2; rt++)
#pragma unroll
        for (int n0 = 0; n0 < 8; n0++) acc[rt][n0] = (floatx4)(0.f);
#pragma unroll
    for (int ks = 0; ks < 4; ks++) {
        short8 ax[2], am[2];
#pragma unroll
        for (int rt = 0; rt < 2; rt++) {
            int n = r0 + rbase + rt * 16 + arow; if (n >= NN) n = NN - 1;
            ax[rt] = cvt8(&x[(size_t)n * 128 + ks * 32 + kblk * 8]);
            am[rt] = *(const short8*)&tile[(rbase + rt * 16 + arow) * 136 + ks * 32 + kblk * 8];
        }
#pragma unroll
        for (int n0 = 0; n0 < 8; n0++) {
            short8 bx = *(const short8*)&wn0t[(size_t)(n0 * 16 + arow) * 256 + ks * 32 + kblk * 8];
            short8 bm = *(const short8*)&wn0t[(size_t)(n0 * 16 + arow) * 256 + 128 + ks * 32 + kblk * 8];
#pragma unroll
            for (int rt = 0; rt < 2; rt++) {
                acc[rt][n0] = MFMA(ax[rt], bx, acc[rt][n0], 0, 0, 0);
                acc[rt][n0] = MFMA(am[rt], bm, acc[rt][n0], 0, 0, 0);
            }
        }
    }
    __syncthreads();   // all stage-2 tile reads complete before h overwrite
#pragma unroll
    for (int rt = 0; rt < 2; rt++)
#pragma unroll
        for (int n0 = 0; n0 < 8; n0++)
#pragma unroll
            for (int j = 0; j < 4; j++) {
                int rloc = rbase + rt * 16 + kblk * 4 + j;
                int col = n0 * 16 + arow;
                float h = acc[rt][n0][j];
                tile[rloc * 136 + col] = f2bf(h > 0.f ? h : expm1f(h));
            }
    __syncthreads();
    // ---- stage 3: out = x + h@Wn1
#pragma unroll
    for (int rt = 0; rt < 2; rt++)
#pragma unroll
        for (int n0 = 0; n0 < 8; n0++) acc[rt][n0] = (floatx4)(0.f);
#pragma unroll
    for (int ks = 0; ks < 4; ks++) {
        short8 a[2];
#pragma unroll
        for (int rt = 0; rt < 2; rt++)
            a[rt] = *(const short8*)&tile[(rbase + rt * 16 + arow) * 136 + ks * 32 + kblk * 8];
#pragma unroll
        for (int n0 = 0; n0 < 8; n0++) {
            short8 b = *(const short8*)&wn1t[(size_t)(n0 * 16 + arow) * 128 + ks * 32 + kblk * 8];
            acc[0][n0] = MFMA(a[0], b, acc[0][n0], 0, 0, 0);
            acc[1][n0] = MFMA(a[1], b, acc[1][n0], 0, 0, 0);
        }
    }
#pragma unroll
    for (int rt = 0; rt < 2; rt++)
#pragma unroll
        for (int n0 = 0; n0 < 8; n0++)
#pragma unroll
            for (int j = 0; j < 4; j++) {
                int n = r0 + rbase + rt * 16 + kblk * 4 + j;
                if (n >= NN) continue;
                int col = n0 * 16 + arow;
                out[(size_t)n * 128 + col] = x[(size_t)n * 128 + col] + acc[rt][n0][j];
            }
}

extern "C" void kernel_launch(void* const* d_in, const int* in_sizes, int n_in,
                              void* d_out, int out_size, void* d_ws, size_t ws_size,
                              hipStream_t stream) {
    const float* x       = (const float*)d_in[0];
    const int* ei        = (const int*)d_in[1];   // int64 in reference -> int32 from harness
    const float* we0     = (const float*)d_in[2];
    const float* we1     = (const float*)d_in[3];
    const float* wn0     = (const float*)d_in[4];
    const float* wn1     = (const float*)d_in[5];
    float* out           = (float*)d_out;

    char* w = (char*)d_ws;
    size_t off = 0;
    auto alloc = [&](size_t bytes) -> void* {
        off = (off + 255) & ~(size_t)255;
        void* p = w + off;
        off += bytes;
        return p;
    };
    u16*   wcombt = (u16*)alloc(256 * 128 * sizeof(u16));
    u16*   we1t   = (u16*)alloc(128 * 128 * sizeof(u16));
    u16*   wn0t   = (u16*)alloc(128 * 256 * sizeof(u16));
    u16*   wn1t   = (u16*)alloc(128 * 128 * sizeof(u16));
    u16*   p2     = (u16*)alloc((size_t)NN * 256 * sizeof(u16));
    u16*   qb     = (u16*)alloc((size_t)NN * 128 * sizeof(u16));
    u16*   esumx  = (u16*)alloc((size_t)NN * 256 * sizeof(u16));
    int*   cnt    = (int*)alloc((size_t)NN * sizeof(int));
    int*   incl   = (int*)alloc((size_t)NN * sizeof(int));
    int*   offs   = (int*)alloc((size_t)(NN + 1) * sizeof(int));
    int*   cursor = (int*)alloc((size_t)NN * sizeof(int));
    int*   bsum   = (int*)alloc(128 * sizeof(int));
    int*   srcs   = (int*)alloc((size_t)NE * sizeof(int));
    (void)ws_size; (void)in_sizes; (void)n_in; (void)out_size;  // ~68 MB of d_ws used

    hipMemsetAsync(cnt, 0, (size_t)NN * sizeof(int), stream);

    k_wb<<<384, 256, 0, stream>>>(we0, we1, wn0, wn1, wcombt, we1t, wn0t, wn1t);
    k_pq_mfma<<<(NN + 127) / 128, 512, 0, stream>>>(x, wcombt, p2, qb);
    k_hist<<<(NE + 255) / 256, 256, 0, stream>>>(ei, cnt);
    int nb = (NN + 511) / 512;
    k_scan1<<<nb, 512, 0, stream>>>(cnt, incl, bsum);
    k_scan2<<<1, 128, 0, stream>>>(bsum, nb);
    k_scan3<<<nb, 512, 0, stream>>>(incl, bsum, cnt, offs, cursor);
    k_slots<<<(NE + 255) / 256, 256, 0, stream>>>(ei, cursor, srcs);
    k_agg<<<(NN + 3) / 4, 256, 0, stream>>>(p2, qb, offs, srcs, esumx);
    k_node_mfma<<<(NN + 127) / 128, 256, 0, stream>>>(x, esumx, we1t, wn0t, wn1t, out);
}

// Round 4
// 272.088 us; speedup vs baseline: 1.9647x; 1.1549x over previous
//
#include <hip/hip_runtime.h>
#include <hip/hip_bf16.h>

// Problem constants (from reference)
#define NN 50000
#define NE 800000
#define HD 128

typedef unsigned short u16;
typedef __attribute__((ext_vector_type(8))) short short8;
typedef __attribute__((ext_vector_type(4))) float floatx4;
#define MFMA __builtin_amdgcn_mfma_f32_16x16x32_bf16

__device__ __forceinline__ float bf2f(u16 v) {
    union { unsigned int u; float f; } x; x.u = ((unsigned int)v) << 16; return x.f;
}
__device__ __forceinline__ u16 f2bf(float f) {
    union { unsigned int u; float f; } x; x.f = f;
    unsigned int r = x.u + 0x7fff + ((x.u >> 16) & 1);
    return (u16)(r >> 16);
}
// fast ELU: t>0 ? t : exp2(t*log2e)-1  (v_exp_f32 path, ~4 instrs)
__device__ __forceinline__ float elu_fast(float t) {
    return t > 0.f ? t : (__builtin_amdgcn_exp2f(t * 1.44269504088896f) - 1.f);
}

// convert 8 consecutive f32 to a bf16 A-fragment
__device__ __forceinline__ short8 cvt8(const float* p) {
    const float4* q = (const float4*)p;
    float4 a = q[0], b = q[1];
    short8 r;
    r[0] = (short)f2bf(a.x); r[1] = (short)f2bf(a.y); r[2] = (short)f2bf(a.z); r[3] = (short)f2bf(a.w);
    r[4] = (short)f2bf(b.x); r[5] = (short)f2bf(b.y); r[6] = (short)f2bf(b.z); r[7] = (short)f2bf(b.w);
    return r;
}

// K0: weight prep -> bf16 transposed layouts [c][k]
__global__ void k_wb(const float* __restrict__ we0, const float* __restrict__ we1,
                     const float* __restrict__ wn0, const float* __restrict__ wn1,
                     u16* __restrict__ wcombt, u16* __restrict__ we1t,
                     u16* __restrict__ wn0t, u16* __restrict__ wn1t) {
    int i = blockIdx.x * 256 + threadIdx.x;
    if (i < 32768) {                       // wcombt
        int c = i >> 7, k = i & 127;
        float v;
        if (c < 128) v = we0[k * 128 + c] + we0[(256 + k) * 128 + c];
        else { int cc = c - 128; v = we0[(128 + k) * 128 + cc] - we0[(256 + k) * 128 + cc]; }
        wcombt[i] = f2bf(v);
    } else if (i < 49152) {                // we1t
        int j = i - 32768; int c = j >> 7, k = j & 127;
        we1t[j] = f2bf(we1[k * 128 + c]);
    } else if (i < 81920) {                // wn0t (k = 0..255)
        int j = i - 49152; int c = j >> 8, k = j & 255;
        wn0t[j] = f2bf(wn0[k * 128 + c]);
    } else if (i < 98304) {                // wn1t
        int j = i - 81920; int c = j >> 7, k = j & 127;
        wn1t[j] = f2bf(wn1[k * 128 + c]);
    }
}

// K2: MFMA [P|Q] = x @ Wcomb.
// p2 layout INTERLEAVED quads: p2[n][4i+0,1] = P[2i],P[2i+1] ; p2[n][4i+2,3] = x[2i],x[2i+1] (bf16)
// qb[n][128] = Q (bf16)
__global__ __launch_bounds__(512) void k_pq_mfma(const float* __restrict__ x,
                                                 const u16* __restrict__ wcombt,
                                                 u16* __restrict__ p2, u16* __restrict__ qb) {
    int r0 = blockIdx.x * 128;
    int tid = threadIdx.x, wid = tid >> 6, lane = tid & 63;
    int arow = lane & 15, kblk = lane >> 4;
    // copy x -> interleaved x-slots of p2 (bf16 pairs)
    for (int s = tid; s < 128 * 64; s += 512) {
        int r = s >> 6, i = s & 63;          // pair index
        int n = r0 + r;
        if (n < NN) {
            float2 v = *(const float2*)&x[(size_t)n * 128 + 2 * i];
            ushort2 o = { f2bf(v.x), f2bf(v.y) };
            *(ushort2*)&p2[(size_t)n * 256 + 4 * i + 2] = o;
        }
    }
    floatx4 acc[16];
#pragma unroll
    for (int n0 = 0; n0 < 16; n0++) acc[n0] = (floatx4)(0.f);
    int nrow = r0 + wid * 16 + arow; if (nrow >= NN) nrow = NN - 1;
#pragma unroll
    for (int ks = 0; ks < 4; ks++) {
        short8 a = cvt8(&x[(size_t)nrow * 128 + ks * 32 + kblk * 8]);
#pragma unroll
        for (int n0 = 0; n0 < 16; n0++) {
            short8 b = *(const short8*)&wcombt[(size_t)(n0 * 16 + arow) * 128 + ks * 32 + kblk * 8];
            acc[n0] = MFMA(a, b, acc[n0], 0, 0, 0);
        }
    }
#pragma unroll
    for (int n0 = 0; n0 < 16; n0++) {
#pragma unroll
        for (int j = 0; j < 4; j++) {
            int n = r0 + wid * 16 + kblk * 4 + j;
            if (n >= NN) continue;
            int col = n0 * 16 + arow;
            u16 v = f2bf(acc[n0][j]);
            if (col < 128) p2[(size_t)n * 256 + 4 * (col >> 1) + (col & 1)] = v;
            else qb[(size_t)n * 128 + (col - 128)] = v;
        }
    }
}

// K3: in-degree histogram, 4 edges/thread
__global__ void k_hist(const int* __restrict__ ei, int* __restrict__ cnt) {
    int e = (blockIdx.x * 256 + threadIdx.x) * 4;
    if (e + 4 <= NE) {
        int4 d = *(const int4*)&ei[NE + e];
        atomicAdd(&cnt[d.x], 1); atomicAdd(&cnt[d.y], 1);
        atomicAdd(&cnt[d.z], 1); atomicAdd(&cnt[d.w], 1);
    } else {
        for (int t = e; t < NE; t++) atomicAdd(&cnt[ei[NE + t]], 1);
    }
}

// K4a: per-block (512) inclusive scan
__global__ void k_scan1(const int* __restrict__ cnt, int* __restrict__ incl, int* __restrict__ bsum) {
    __shared__ int s[512];
    int i = blockIdx.x * 512 + threadIdx.x;
    int v = (i < NN) ? cnt[i] : 0;
    s[threadIdx.x] = v; __syncthreads();
    for (int off = 1; off < 512; off <<= 1) {
        int t = (threadIdx.x >= (unsigned)off) ? s[threadIdx.x - off] : 0;
        __syncthreads();
        s[threadIdx.x] += t; __syncthreads();
    }
    if (i < NN) incl[i] = s[threadIdx.x];
    if (threadIdx.x == 511) bsum[blockIdx.x] = s[511];
}

// K4b: exclusive scan of block sums (nb <= 128)
__global__ void k_scan2(int* __restrict__ bsum, int nb) {
    __shared__ int s[128];
    int t = threadIdx.x;
    s[t] = (t < nb) ? bsum[t] : 0;
    __syncthreads();
    if (t == 0) { int run = 0; for (int b = 0; b < nb; b++) { int v = s[b]; s[b] = run; run += v; } }
    __syncthreads();
    if (t < nb) bsum[t] = s[t];
}

// K4c
__global__ void k_scan3(const int* __restrict__ incl, const int* __restrict__ bsum,
                        const int* __restrict__ cnt, int* __restrict__ offs, int* __restrict__ cursor) {
    int i = blockIdx.x * 512 + threadIdx.x;
    if (i < NN) {
        int e = incl[i] + bsum[i >> 9];
        offs[i + 1] = e;
        cursor[i] = e - cnt[i];
        if (i == 0) offs[0] = 0;
    }
}

// K5: scatter edge srcs into CSR slots grouped by dst (2 edges/thread)
__global__ void k_slots(const int* __restrict__ ei, int* __restrict__ cursor, int* __restrict__ srcs) {
    int e = (blockIdx.x * 256 + threadIdx.x) * 2;
    if (e + 2 <= NE) {
        int2 sv = *(const int2*)&ei[e];
        int2 dv = *(const int2*)&ei[NE + e];
        int p0 = atomicAdd(&cursor[dv.x], 1); srcs[p0] = sv.x;
        int p1 = atomicAdd(&cursor[dv.y], 1); srcs[p1] = sv.y;
    } else {
        for (int t = e; t < NE; t++) {
            int p = atomicAdd(&cursor[ei[NE + t]], 1);
            srcs[p] = ei[t];
        }
    }
}

// K6: one wave per node. Each lane owns channels 2l,2l+1 of BOTH esum and xsum
// via the interleaved p2 quads. Outputs (unchanged layout):
//   esumx[n][0:128]   = esum/max(cnt,1)
//   esumx[n][128:256] = (xsum - cnt*x[n])/max(cnt,1)
__global__ __launch_bounds__(256) void k_agg(const u16* __restrict__ p2, const u16* __restrict__ qb,
                                             const int* __restrict__ offs, const int* __restrict__ srcs,
                                             u16* __restrict__ esumx) {
    int wave = threadIdx.x >> 6, lane = threadIdx.x & 63;
    int n = blockIdx.x * 4 + wave;
    if (n >= NN) return;
    int beg = offs[n], end = offs[n + 1];
    ushort2 qv = *(const ushort2*)(qb + (size_t)n * 128 + 2 * lane);
    float q0 = bf2f(qv.x), q1 = bf2f(qv.y);
    float e0 = 0.f, e1 = 0.f, s0 = 0.f, s1 = 0.f;
    int s = beg;
    for (; s + 8 <= end; s += 8) {
        int sr[8];
#pragma unroll
        for (int j = 0; j < 8; j++) sr[j] = srcs[s + j];
        ushort4 v[8];
#pragma unroll
        for (int j = 0; j < 8; j++) v[j] = *(const ushort4*)(p2 + (size_t)sr[j] * 256 + 4 * lane);
#pragma unroll
        for (int j = 0; j < 8; j++) {
            float t0 = bf2f(v[j].x) + q0, t1 = bf2f(v[j].y) + q1;
            e0 += elu_fast(t0); e1 += elu_fast(t1);
            s0 += bf2f(v[j].z); s1 += bf2f(v[j].w);
        }
    }
    for (; s < end; ++s) {
        ushort4 v = *(const ushort4*)(p2 + (size_t)srcs[s] * 256 + 4 * lane);
        float t0 = bf2f(v.x) + q0, t1 = bf2f(v.y) + q1;
        e0 += elu_fast(t0); e1 += elu_fast(t1);
        s0 += bf2f(v.z); s1 += bf2f(v.w);
    }
    float cntf = (float)(end - beg);
    float inv = 1.f / fmaxf(cntf, 1.f);
    ushort2 xo = *(const ushort2*)(p2 + (size_t)n * 256 + 4 * lane + 2);  // own x, ch 2l,2l+1
    s0 = (s0 - cntf * bf2f(xo.x)) * inv;
    s1 = (s1 - cntf * bf2f(xo.y)) * inv;
    e0 *= inv; e1 *= inv;
    ushort2 oe = { f2bf(e0), f2bf(e1) };
    ushort2 os = { f2bf(s0), f2bf(s1) };
    *(ushort2*)(esumx + (size_t)n * 256 + 2 * lane) = oe;
    *(ushort2*)(esumx + (size_t)n * 256 + 128 + 2 * lane) = os;
}

// K7: MFMA node MLP. block: 256 thr = 4 waves x 32 rows (2 row-tiles); 128 rows/block.
__global__ __launch_bounds__(256) void k_node_mfma(const float* __restrict__ x,
                                                   const u16* __restrict__ esumx,
                                                   const u16* __restrict__ we1t,
                                                   const u16* __restrict__ wn0t,
                                                   const u16* __restrict__ wn1t,
                                                   float* __restrict__ out) {
    __shared__ u16 tile[128 * 136];   // pad 8 bf16 -> 2-way max bank aliasing (free)
    int r0 = blockIdx.x * 128;
    int tid = threadIdx.x, wid = tid >> 6, lane = tid & 63;
    int arow = lane & 15, kblk = lane >> 4;
    // stage xsum' (esumx hi half) into tile
    for (int s = tid; s < 128 * 16; s += 256) {
        int r = s >> 4, cb = (s & 15) * 8;
        int n = r0 + r; if (n >= NN) n = NN - 1;
        *(short8*)&tile[r * 136 + cb] = *(const short8*)&esumx[(size_t)n * 256 + 128 + cb];
    }
    __syncthreads();
    int rbase = wid * 32;
    floatx4 acc[2][8];
#pragma unroll
    for (int rt = 0; rt < 2; rt++)
#pragma unroll
        for (int n0 = 0; n0 < 8; n0++) acc[rt][n0] = (floatx4)(0.f);
    // ---- stage 1: T = esum/cnt @ We1
#pragma unroll
    for (int ks = 0; ks < 4; ks++) {
        short8 a[2];
#pragma unroll
        for (int rt = 0; rt < 2; rt++) {
            int n = r0 + rbase + rt * 16 + arow; if (n >= NN) n = NN - 1;
            a[rt] = *(const short8*)&esumx[(size_t)n * 256 + ks * 32 + kblk * 8];
        }
#pragma unroll
        for (int n0 = 0; n0 < 8; n0++) {
            short8 b = *(const short8*)&we1t[(size_t)(n0 * 16 + arow) * 128 + ks * 32 + kblk * 8];
            acc[0][n0] = MFMA(a[0], b, acc[0][n0], 0, 0, 0);
            acc[1][n0] = MFMA(a[1], b, acc[1][n0], 0, 0, 0);
        }
    }
    // ---- m = T + xsum' (in place in tile)
#pragma unroll
    for (int rt = 0; rt < 2; rt++)
#pragma unroll
        for (int n0 = 0; n0 < 8; n0++)
#pragma unroll
            for (int j = 0; j < 4; j++) {
                int rloc = rbase + rt * 16 + kblk * 4 + j;
                int col = n0 * 16 + arow;
                float m = acc[rt][n0][j] + bf2f(tile[rloc * 136 + col]);
                tile[rloc * 136 + col] = f2bf(m);
            }
    __syncthreads();
    // ---- stage 2: h = ELU(x@Wn0a + m@Wn0b)
#pragma unroll
    for (int rt = 0; rt < 2; rt++)
#pragma unroll
        for (int n0 = 0; n0 < 8; n0++) acc[rt][n0] = (floatx4)(0.f);
#pragma unroll
    for (int ks = 0; ks < 4; ks++) {
        short8 ax[2], am[2];
#pragma unroll
        for (int rt = 0; rt < 2; rt++) {
            int n = r0 + rbase + rt * 16 + arow; if (n >= NN) n = NN - 1;
            ax[rt] = cvt8(&x[(size_t)n * 128 + ks * 32 + kblk * 8]);
            am[rt] = *(const short8*)&tile[(rbase + rt * 16 + arow) * 136 + ks * 32 + kblk * 8];
        }
#pragma unroll
        for (int n0 = 0; n0 < 8; n0++) {
            short8 bx = *(const short8*)&wn0t[(size_t)(n0 * 16 + arow) * 256 + ks * 32 + kblk * 8];
            short8 bm = *(const short8*)&wn0t[(size_t)(n0 * 16 + arow) * 256 + 128 + ks * 32 + kblk * 8];
#pragma unroll
            for (int rt = 0; rt < 2; rt++) {
                acc[rt][n0] = MFMA(ax[rt], bx, acc[rt][n0], 0, 0, 0);
                acc[rt][n0] = MFMA(am[rt], bm, acc[rt][n0], 0, 0, 0);
            }
        }
    }
    __syncthreads();   // all stage-2 tile reads complete before h overwrite
#pragma unroll
    for (int rt = 0; rt < 2; rt++)
#pragma unroll
        for (int n0 = 0; n0 < 8; n0++)
#pragma unroll
            for (int j = 0; j < 4; j++) {
                int rloc = rbase + rt * 16 + kblk * 4 + j;
                int col = n0 * 16 + arow;
                float h = acc[rt][n0][j];
                tile[rloc * 136 + col] = f2bf(elu_fast(h));
            }
    __syncthreads();
    // ---- stage 3: out = x + h@Wn1
#pragma unroll
    for (int rt = 0; rt < 2; rt++)
#pragma unroll
        for (int n0 = 0; n0 < 8; n0++) acc[rt][n0] = (floatx4)(0.f);
#pragma unroll
    for (int ks = 0; ks < 4; ks++) {
        short8 a[2];
#pragma unroll
        for (int rt = 0; rt < 2; rt++)
            a[rt] = *(const short8*)&tile[(rbase + rt * 16 + arow) * 136 + ks * 32 + kblk * 8];
#pragma unroll
        for (int n0 = 0; n0 < 8; n0++) {
            short8 b = *(const short8*)&wn1t[(size_t)(n0 * 16 + arow) * 128 + ks * 32 + kblk * 8];
            acc[0][n0] = MFMA(a[0], b, acc[0][n0], 0, 0, 0);
            acc[1][n0] = MFMA(a[1], b, acc[1][n0], 0, 0, 0);
        }
    }
#pragma unroll
    for (int rt = 0; rt < 2; rt++)
#pragma unroll
        for (int n0 = 0; n0 < 8; n0++)
#pragma unroll
            for (int j = 0; j < 4; j++) {
                int n = r0 + rbase + rt * 16 + kblk * 4 + j;
                if (n >= NN) continue;
                int col = n0 * 16 + arow;
                out[(size_t)n * 128 + col] = x[(size_t)n * 128 + col] + acc[rt][n0][j];
            }
}

extern "C" void kernel_launch(void* const* d_in, const int* in_sizes, int n_in,
                              void* d_out, int out_size, void* d_ws, size_t ws_size,
                              hipStream_t stream) {
    const float* x       = (const float*)d_in[0];
    const int* ei        = (const int*)d_in[1];   // int64 in reference -> int32 from harness
    const float* we0     = (const float*)d_in[2];
    const float* we1     = (const float*)d_in[3];
    const float* wn0     = (const float*)d_in[4];
    const float* wn1     = (const float*)d_in[5];
    float* out           = (float*)d_out;

    char* w = (char*)d_ws;
    size_t off = 0;
    auto alloc = [&](size_t bytes) -> void* {
        off = (off + 255) & ~(size_t)255;
        void* p = w + off;
        off += bytes;
        return p;
    };
    u16*   wcombt = (u16*)alloc(256 * 128 * sizeof(u16));
    u16*   we1t   = (u16*)alloc(128 * 128 * sizeof(u16));
    u16*   wn0t   = (u16*)alloc(128 * 256 * sizeof(u16));
    u16*   wn1t   = (u16*)alloc(128 * 128 * sizeof(u16));
    u16*   p2     = (u16*)alloc((size_t)NN * 256 * sizeof(u16));
    u16*   qb     = (u16*)alloc((size_t)NN * 128 * sizeof(u16));
    u16*   esumx  = (u16*)alloc((size_t)NN * 256 * sizeof(u16));
    int*   cnt    = (int*)alloc((size_t)NN * sizeof(int));
    int*   incl   = (int*)alloc((size_t)NN * sizeof(int));
    int*   offs   = (int*)alloc((size_t)(NN + 1) * sizeof(int));
    int*   cursor = (int*)alloc((size_t)NN * sizeof(int));
    int*   bsum   = (int*)alloc(128 * sizeof(int));
    int*   srcs   = (int*)alloc((size_t)NE * sizeof(int));
    (void)ws_size; (void)in_sizes; (void)n_in; (void)out_size;  // ~68 MB of d_ws used

    hipMemsetAsync(cnt, 0, (size_t)NN * sizeof(int), stream);

    k_wb<<<384, 256, 0, stream>>>(we0, we1, wn0, wn1, wcombt, we1t, wn0t, wn1t);
    k_pq_mfma<<<(NN + 127) / 128, 512, 0, stream>>>(x, wcombt, p2, qb);
    k_hist<<<(NE / 4 + 255) / 256, 256, 0, stream>>>(ei, cnt);
    int nb = (NN + 511) / 512;
    k_scan1<<<nb, 512, 0, stream>>>(cnt, incl, bsum);
    k_scan2<<<1, 128, 0, stream>>>(bsum, nb);
    k_scan3<<<nb, 512, 0, stream>>>(incl, bsum, cnt, offs, cursor);
    k_slots<<<(NE / 2 + 255) / 256, 256, 0, stream>>>(ei, cursor, srcs);
    k_agg<<<(NN + 3) / 4, 256, 0, stream>>>(p2, qb, offs, srcs, esumx);
    k_node_mfma<<<(NN + 127) / 128, 256, 0, stream>>>(x, esumx, we1t, wn0t, wn1t, out);
}